// Round 1
// baseline (3400.703 us; speedup 1.0000x reference)
//
#include <hip/hip_runtime.h>

// Problem constants
#define BB   512            // batch
#define TT   128            // time steps
#define DD   512            // d_dyn
#define DS   256            // d_static
#define UD   128            // u_dim
#define NO   40             // n_obs
#define G4   2048           // 4*DD
#define K0   640            // UD + DD (layer-0 concat K)
#define K1   512            // layer-1 K
#define KY   640            // DD + UD (output head K)
#define NY   48             // padded n_obs for MFMA tiles

typedef __bf16 bf16x8 __attribute__((ext_vector_type(8)));
typedef float  f32x4  __attribute__((ext_vector_type(4)));

__device__ __forceinline__ f32x4 mfma16(bf16x8 a, bf16x8 b, f32x4 c) {
  return __builtin_amdgcn_mfma_f32_16x16x32_bf16(a, b, c, 0, 0, 0);
}

__device__ __forceinline__ float sigm(float x)     { return 1.0f / (1.0f + __expf(-x)); }
__device__ __forceinline__ float tanhfast(float x) { return 2.0f / (1.0f + __expf(-2.0f * x)) - 1.0f; }

// load 8 consecutive f32, convert to bf16x8
__device__ __forceinline__ bf16x8 cvt8(const float* __restrict__ p) {
  const float4 u0 = *reinterpret_cast<const float4*>(p);
  const float4 u1 = *reinterpret_cast<const float4*>(p + 4);
  bf16x8 r;
  r[0] = (__bf16)u0.x; r[1] = (__bf16)u0.y; r[2] = (__bf16)u0.z; r[3] = (__bf16)u0.w;
  r[4] = (__bf16)u1.x; r[5] = (__bf16)u1.y; r[6] = (__bf16)u1.z; r[7] = (__bf16)u1.w;
  return r;
}
__device__ __forceinline__ bf16x8 cvt8s(const float* __restrict__ p, float s) {
  const float4 u0 = *reinterpret_cast<const float4*>(p);
  const float4 u1 = *reinterpret_cast<const float4*>(p + 4);
  bf16x8 r;
  r[0] = (__bf16)(u0.x*s); r[1] = (__bf16)(u0.y*s); r[2] = (__bf16)(u0.z*s); r[3] = (__bf16)(u0.w*s);
  r[4] = (__bf16)(u1.x*s); r[5] = (__bf16)(u1.y*s); r[6] = (__bf16)(u1.z*s); r[7] = (__bf16)(u1.w*s);
  return r;
}

// ---------------- one-time prep: weight concat/sum + state init ----------------
__global__ __launch_bounds__(256) void prep_kernel(
    const float* __restrict__ Wih0, const float* __restrict__ Whh0,
    const float* __restrict__ Wih1, const float* __restrict__ Whh1,
    const float* __restrict__ bih1, const float* __restrict__ bhh1,
    const float* __restrict__ Cw,   const float* __restrict__ Dw,
    const float* __restrict__ z_dyn,
    __bf16* __restrict__ W0cat, __bf16* __restrict__ W1sum, float* __restrict__ b1sum,
    __bf16* __restrict__ CD, float* __restrict__ c1, float* __restrict__ c2,
    __bf16* __restrict__ h_prev)
{
  int idx = blockIdx.x * 256 + threadIdx.x;
  if (idx < G4 * K0) {            // W0cat[j, k] : k<128 -> Wih0[:, :128], else Whh0
    int j = idx / K0, k = idx - j * K0;
    float v = (k < UD) ? Wih0[j * (UD + DS) + k] : Whh0[j * DD + (k - UD)];
    W0cat[idx] = (__bf16)v;
  }
  if (idx < G4 * K1) {            // W1sum = Wih1 + Whh1 (same row-major layout)
    W1sum[idx] = (__bf16)(Wih1[idx] + Whh1[idx]);
  }
  if (idx < G4) b1sum[idx] = bih1[idx] + bhh1[idx];
  if (idx < NY * KY) {            // CD[o, k] : k<512 -> C, else D ; rows 40:48 = 0
    int o = idx / KY, k = idx - o * KY;
    float v = 0.f;
    if (o < NO) v = (k < DD) ? Cw[o * DD + k] : Dw[o * UD + (k - DD)];
    CD[idx] = (__bf16)v;
  }
  if (idx < BB * DD) {            // c states zero, h_prev = bf16(z_dyn)
    c1[idx] = 0.f; c2[idx] = 0.f;
    h_prev[idx] = (__bf16)z_dyn[idx];
  }
}

// ---------------- one-time: pre0[b,j] = z_static @ Wih0[:,128:384]^T + bih0 + bhh0 ----
// grid (8, 32), block 256 (4 waves). wave tile: 16 rows x 64 j-cols (4 col frags).
__global__ __launch_bounds__(256) void pre0_kernel(
    const float* __restrict__ z_static, const float* __restrict__ Wih0,
    const float* __restrict__ bih0, const float* __restrict__ bhh0,
    float* __restrict__ pre0)
{
  int lane = threadIdx.x & 63, w = threadIdx.x >> 6;
  int rm = lane & 15;
  int row = blockIdx.x * 64 + w * 16 + rm;
  int j0 = blockIdx.y * 64;
  int klane = (lane >> 4) * 8;
  f32x4 acc[4] = {};
  for (int k0 = 0; k0 < DS; k0 += 32) {
    int k = k0 + klane;
    bf16x8 a = cvt8(&z_static[row * DS + k]);
#pragma unroll
    for (int cf = 0; cf < 4; ++cf) {
      int j = j0 + cf * 16 + rm;
      bf16x8 b = cvt8(&Wih0[j * (UD + DS) + UD + k]);
      acc[cf] = mfma16(a, b, acc[cf]);
    }
  }
  int rbase = blockIdx.x * 64 + w * 16 + (lane >> 4) * 4;
#pragma unroll
  for (int cf = 0; cf < 4; ++cf) {
    int j = j0 + cf * 16 + rm;
    float bj = bih0[j] + bhh0[j];
#pragma unroll
    for (int q = 0; q < 4; ++q) {
      pre0[(size_t)(rbase + q) * G4 + j] = acc[cf][q] + bj;
    }
  }
}

// ---------------- per-step fused GEMM + LSTM cell ----------------
// grid (8, 32), block 256 (4 waves). wave tile: 16 rows x 16 d-cols x 4 gates.
// L0: X = [ut*dt (K 0:128 from U), h_prev (K 128:640)], W = W0cat, bias = pre0[b, :]
// L1: X = h1, W = W1sum, bias = b1sum[:]
template <bool L0>
__global__ __launch_bounds__(256) void lstm_layer_kernel(
    const float* __restrict__ Ut,          // U + t*BB*UD (L0 only)
    const float* __restrict__ dtp,
    const __bf16* __restrict__ Xh,         // h_prev (L0) or h1 (L1), [BB, DD]
    const __bf16* __restrict__ W,          // [G4, KT]
    const float* __restrict__ pre,         // L0: pre0 [BB, G4]; L1: b1sum [G4]
    float* __restrict__ cbuf,              // [BB, DD] in/out
    __bf16* __restrict__ hbf,              // h out bf16 [BB, DD]
    float* __restrict__ hf32)              // L1: Z + t*BB*DD ; L0: unused
{
  constexpr int KT = L0 ? K0 : K1;
  int lane = threadIdx.x & 63, w = threadIdx.x >> 6;
  int rm = lane & 15;
  int row = blockIdx.x * 64 + w * 16 + rm;
  int d0 = blockIdx.y * 16;
  int klane = (lane >> 4) * 8;
  float dtv = L0 ? dtp[0] : 0.f;
  const __bf16* xrow = Xh + (size_t)row * DD;
  f32x4 acc[4] = {};
#pragma unroll
  for (int k0 = 0; k0 < KT; k0 += 32) {
    int k = k0 + klane;
    bf16x8 a;
    if (L0 && k0 < UD) {
      a = cvt8s(&Ut[(size_t)row * UD + k], dtv);
    } else {
      a = *reinterpret_cast<const bf16x8*>(&xrow[L0 ? (k - UD) : k]);
    }
#pragma unroll
    for (int g = 0; g < 4; ++g) {
      bf16x8 b = *reinterpret_cast<const bf16x8*>(&W[(size_t)(g * DD + d0 + rm) * KT + k]);
      acc[g] = mfma16(a, b, acc[g]);
    }
  }
  int dcol = d0 + rm;
  int rbase = blockIdx.x * 64 + w * 16 + (lane >> 4) * 4;
#pragma unroll
  for (int q = 0; q < 4; ++q) {
    int r = rbase + q;
    float gi = acc[0][q], gf = acc[1][q], gg = acc[2][q], go = acc[3][q];
    if (L0) {
      const float* pr = pre + (size_t)r * G4;
      gi += pr[dcol]; gf += pr[DD + dcol]; gg += pr[2 * DD + dcol]; go += pr[3 * DD + dcol];
    } else {
      gi += pre[dcol]; gf += pre[DD + dcol]; gg += pre[2 * DD + dcol]; go += pre[3 * DD + dcol];
    }
    size_t off = (size_t)r * DD + dcol;
    float cold = cbuf[off];
    float cn = sigm(gf) * cold + sigm(gi) * tanhfast(gg);
    float hn = sigm(go) * tanhfast(cn);
    cbuf[off] = cn;
    hbf[off] = (__bf16)hn;
    if (!L0) hf32[off] = hn;
  }
}

// ---------------- batched output head: Y = [Z | dt*U] @ CD^T ----------------
// grid 512, block 256 (4 waves). wave tile: 32 rows (2 frags) x 48 cols (3 frags).
__global__ __launch_bounds__(256) void y_kernel(
    const float* __restrict__ Z, const float* __restrict__ U,
    const float* __restrict__ dtp, const __bf16* __restrict__ CD,
    float* __restrict__ Y)
{
  int lane = threadIdx.x & 63, w = threadIdx.x >> 6;
  int rm = lane & 15;
  int rowbase = blockIdx.x * 128 + w * 32;
  int klane = (lane >> 4) * 8;
  float dtv = dtp[0];
  f32x4 acc[2][3] = {};
#pragma unroll
  for (int k0 = 0; k0 < KY; k0 += 32) {
    int k = k0 + klane;
    bf16x8 a[2];
#pragma unroll
    for (int rb = 0; rb < 2; ++rb) {
      int r = rowbase + rb * 16 + rm;
      if (k0 < DD) a[rb] = cvt8(&Z[(size_t)r * DD + k]);
      else         a[rb] = cvt8s(&U[(size_t)r * UD + (k - DD)], dtv);
    }
#pragma unroll
    for (int cf = 0; cf < 3; ++cf) {
      bf16x8 b = *reinterpret_cast<const bf16x8*>(&CD[(size_t)(cf * 16 + rm) * KY + k]);
#pragma unroll
      for (int rb = 0; rb < 2; ++rb) acc[rb][cf] = mfma16(a[rb], b, acc[rb][cf]);
    }
  }
#pragma unroll
  for (int rb = 0; rb < 2; ++rb) {
#pragma unroll
    for (int cf = 0; cf < 3; ++cf) {
      int n = cf * 16 + rm;
      if (n < NO) {
#pragma unroll
        for (int q = 0; q < 4; ++q) {
          int r = rowbase + rb * 16 + (lane >> 4) * 4 + q;
          Y[(size_t)r * NO + n] = acc[rb][cf][q];
        }
      }
    }
  }
}

extern "C" void kernel_launch(void* const* d_in, const int* in_sizes, int n_in,
                              void* d_out, int out_size, void* d_ws, size_t ws_size,
                              hipStream_t stream) {
  const float* z_dyn    = (const float*)d_in[0];
  const float* z_static = (const float*)d_in[1];
  const float* dt       = (const float*)d_in[2];
  const float* U        = (const float*)d_in[3];
  const float* Wih0     = (const float*)d_in[4];
  const float* Whh0     = (const float*)d_in[5];
  const float* bih0     = (const float*)d_in[6];
  const float* bhh0     = (const float*)d_in[7];
  const float* Wih1     = (const float*)d_in[8];
  const float* Whh1     = (const float*)d_in[9];
  const float* bih1     = (const float*)d_in[10];
  const float* bhh1     = (const float*)d_in[11];
  const float* Cw       = (const float*)d_in[12];
  const float* Dw       = (const float*)d_in[13];

  float* out = (float*)d_out;
  float* Z = out;                                       // [TT, BB, DD]
  float* Y = out + (size_t)TT * BB * DD;                // [TT, BB, NO]

  // workspace carve (256B aligned)
  char* p = (char*)d_ws;
  auto carve = [&](size_t bytes) {
    void* r = (void*)p;
    p += (bytes + 255) & ~(size_t)255;
    return r;
  };
  __bf16* W0cat  = (__bf16*)carve((size_t)G4 * K0 * 2);
  __bf16* W1sum  = (__bf16*)carve((size_t)G4 * K1 * 2);
  float*  b1sum  = (float*)carve((size_t)G4 * 4);
  __bf16* CD     = (__bf16*)carve((size_t)NY * KY * 2);
  float*  pre0   = (float*)carve((size_t)BB * G4 * 4);
  float*  c1     = (float*)carve((size_t)BB * DD * 4);
  float*  c2     = (float*)carve((size_t)BB * DD * 4);
  __bf16* h_prev = (__bf16*)carve((size_t)BB * DD * 2);
  __bf16* h1     = (__bf16*)carve((size_t)BB * DD * 2);

  // 1. prep (weights + state init)
  {
    int total = G4 * K0;  // largest section
    prep_kernel<<<(total + 255) / 256, 256, 0, stream>>>(
        Wih0, Whh0, Wih1, Whh1, bih1, bhh1, Cw, Dw, z_dyn,
        W0cat, W1sum, b1sum, CD, c1, c2, h_prev);
  }
  // 2. static precompute
  pre0_kernel<<<dim3(8, 32), 256, 0, stream>>>(z_static, Wih0, bih0, bhh0, pre0);

  // 3. sequential scan
  for (int t = 0; t < TT; ++t) {
    const float* Ut = U + (size_t)t * BB * UD;
    lstm_layer_kernel<true><<<dim3(8, 32), 256, 0, stream>>>(
        Ut, dt, h_prev, W0cat, pre0, c1, h1, nullptr);
    lstm_layer_kernel<false><<<dim3(8, 32), 256, 0, stream>>>(
        nullptr, dt, h1, W1sum, b1sum, c2, h_prev, Z + (size_t)t * BB * DD);
  }

  // 4. batched output head
  y_kernel<<<512, 256, 0, stream>>>(Z, U, dt, CD, Y);
}